// Round 27
// baseline (792.245 us; speedup 1.0000x reference)
//
#include <hip/hip_runtime.h>
#include <cstdint>
#include <cstddef>

// Informer ProbSparse decoder layer.
// GEMMs: split-once bf16 limbs + multi-limb bf16 GEMM, 128x128 tile.
// Round-27: QK gemm K-split x3 (gemm_qk, grid (8,32,6)=1536 blocks = exact
// 3 blocks/CU sustained -- round-22/26 showed the 512-block grid capped
// occupancy at 2/CU, 48% MfmaUtil). f32 partials into dead buffers +
// vectorized qk_combine (+bias). topk: wave-shuffle argmax (1 barrier/iter
// vs 9). NL=1 gemms: gemm_one dbuf (round-26, neutral but harmless).
// Weight splits batched (round-24). XOR chunk swizzle (src-side, rule #21)
// + XCD swizzle. Q/K: 6 pairings (~f32); V/O/FFN: 1. Attention: 3-kernel
// k-split; attn_score/attn_pv 4-lane-cooperative with XCD affinity.
#define B_     4
#define L_     1024
#define DM_    1024
#define H_     16
#define DH_    64
#define U_     35
#define FF_    4096
#define MROWS_ 4096
#define IDXN_  35840
#define KSC_   16
#define KSP_   16

typedef __attribute__((ext_vector_type(8))) short bf16x8;
typedef __attribute__((ext_vector_type(4))) float f32x4;

// ---------------- Threefry-2x32-20 (exact JAX semantics) ----------------
__host__ __device__ inline void tf2x32(uint32_t k0, uint32_t k1,
                                       uint32_t x0, uint32_t x1,
                                       uint32_t& y0, uint32_t& y1) {
  const uint32_t ks2 = k0 ^ k1 ^ 0x1BD11BDAu;
  uint32_t v0 = x0 + k0, v1 = x1 + k1;
#define ROTL_(x,d) (((x)<<(d))|((x)>>(32-(d))))
#define RND_(r) { v0 += v1; v1 = ROTL_(v1,(r)); v1 ^= v0; }
  RND_(13) RND_(15) RND_(26) RND_(6)   v0 += k1;  v1 += ks2 + 1u;
  RND_(17) RND_(29) RND_(16) RND_(24)  v0 += ks2; v1 += k0  + 2u;
  RND_(13) RND_(15) RND_(26) RND_(6)   v0 += k0;  v1 += k1  + 3u;
  RND_(17) RND_(29) RND_(16) RND_(24)  v0 += k1;  v1 += ks2 + 4u;
  RND_(13) RND_(15) RND_(26) RND_(6)   v0 += ks2; v1 += k0  + 5u;
#undef RND_
#undef ROTL_
  y0 = v0; y1 = v1;
}

__global__ void idx_kernel(uint32_t k0, uint32_t k1, int* __restrict__ idx) {
  const int i = blockIdx.x * 256 + threadIdx.x;
  if (i >= IDXN_) return;
  uint32_t y0, y1;
  tf2x32(k0, k1, 0u, (uint32_t)i, y0, y1);
  idx[i] = (int)((y0 ^ y1) & 1023u);
}

// ---------------- bf16 helpers --------------------------------------------
__device__ __forceinline__ uint32_t f32bits(float x) {
  union { float f; uint32_t u; } c; c.f = x; return c.u;
}
__device__ __forceinline__ float bitsf32(uint32_t u) {
  union { uint32_t u; float f; } c; c.u = u; return c.f;
}
__device__ __forceinline__ uint32_t bf16rne(float x) {
  const uint32_t u = f32bits(x);
  return (u + 0x7FFFu + ((u >> 16) & 1u)) >> 16;
}
__device__ __forceinline__ float bf16tof(uint32_t h) { return bitsf32(h << 16); }

__device__ __forceinline__ void split3(float x, uint32_t& h, uint32_t& m, uint32_t& l) {
  h = bf16rne(x); const float r  = x - bf16tof(h);
  m = bf16rne(r); const float r2 = r - bf16tof(m);
  l = bf16rne(r2);
}

// ---------------- async global -> LDS (16B per lane) ----------------------
__device__ __forceinline__ void gload16(const void* g, void* l) {
  __builtin_amdgcn_global_load_lds(
      (const __attribute__((address_space(1))) void*)g,
      (__attribute__((address_space(3))) void*)l, 16, 0, 0);
}

// ---------------- batched transpose-split (round-24) ----------------------
struct TSJob { const float* W; short* Th; short* Tm; short* Tl; int K; int N; int limbs; int nblk; };
struct TSJobs { TSJob j[4]; int cnt; };

__global__ __launch_bounds__(256) void tsplit_batch(TSJobs jobs)
{
  __shared__ float tile[64][65];
  int local = blockIdx.x;
  int ji = 0;
  while (ji < jobs.cnt - 1 && local >= jobs.j[ji].nblk) { local -= jobs.j[ji].nblk; ++ji; }
  const TSJob J = jobs.j[ji];
  const int ntiles = J.N >> 6;
  const int n0 = (local % ntiles) * 64;
  const int k0 = (local / ntiles) * 64;

  const int t = threadIdx.x;
  const int r = t >> 2, c0 = (t & 3) * 16;
  const float* src = J.W + (size_t)(k0 + r) * J.N + n0 + c0;
  const float4 v0 = *(const float4*)src;
  const float4 v1 = *(const float4*)(src + 4);
  const float4 v2 = *(const float4*)(src + 8);
  const float4 v3 = *(const float4*)(src + 12);
  float* tr = &tile[r][c0];
  tr[0]=v0.x; tr[1]=v0.y; tr[2]=v0.z; tr[3]=v0.w;
  tr[4]=v1.x; tr[5]=v1.y; tr[6]=v1.z; tr[7]=v1.w;
  tr[8]=v2.x; tr[9]=v2.y; tr[10]=v2.z; tr[11]=v2.w;
  tr[12]=v3.x; tr[13]=v3.y; tr[14]=v3.z; tr[15]=v3.w;
  __syncthreads();
  uint32_t ph[8], pm[8], pl[8];
#pragma unroll
  for (int j = 0; j < 16; j += 2) {
    uint32_t h0,m0,l0,h1,m1,l1;
    split3(tile[c0 + j][r], h0, m0, l0);
    split3(tile[c0 + j + 1][r], h1, m1, l1);
    ph[j>>1] = h0 | (h1 << 16);
    pm[j>>1] = m0 | (m1 << 16);
    pl[j>>1] = l0 | (l1 << 16);
  }
  const size_t ob = (size_t)(n0 + r) * J.K + k0 + c0;
  *(uint4*)(J.Th + ob)     = make_uint4(ph[0], ph[1], ph[2], ph[3]);
  *(uint4*)(J.Th + ob + 8) = make_uint4(ph[4], ph[5], ph[6], ph[7]);
  if (J.limbs == 3) {
    *(uint4*)(J.Tm + ob)     = make_uint4(pm[0], pm[1], pm[2], pm[3]);
    *(uint4*)(J.Tm + ob + 8) = make_uint4(pm[4], pm[5], pm[6], pm[7]);
    *(uint4*)(J.Tl + ob)     = make_uint4(pl[0], pl[1], pl[2], pl[3]);
    *(uint4*)(J.Tl + ob + 8) = make_uint4(pl[4], pl[5], pl[6], pl[7]);
  }
}

// ---------------- row split: X (f32) -> limbs (bf16), elementwise ---------
template<int LIMBS>
__global__ void rsplit_kernel(const float* __restrict__ X, short* __restrict__ Th,
                              short* __restrict__ Tm, short* __restrict__ Tl, int n8)
{
  const int i = blockIdx.x * 256 + threadIdx.x;
  if (i >= n8) return;
  const float4 a = ((const float4*)X)[2*i], b = ((const float4*)X)[2*i+1];
  const float v[8] = {a.x,a.y,a.z,a.w,b.x,b.y,b.z,b.w};
  uint32_t ph[4], pm[4], pl[4];
#pragma unroll
  for (int j = 0; j < 4; ++j) {
    uint32_t h0,m0,l0,h1,m1,l1;
    split3(v[2*j], h0, m0, l0);
    split3(v[2*j+1], h1, m1, l1);
    ph[j] = h0 | (h1 << 16); pm[j] = m0 | (m1 << 16); pl[j] = l0 | (l1 << 16);
  }
  ((uint4*)Th)[i] = make_uint4(ph[0], ph[1], ph[2], ph[3]);
  if (LIMBS == 3) {
    ((uint4*)Tm)[i] = make_uint4(pm[0], pm[1], pm[2], pm[3]);
    ((uint4*)Tl)[i] = make_uint4(pl[0], pl[1], pl[2], pl[3]);
  }
}

// ---------------- K-split 3-limb QK GEMM (round-27) -----------------------
// Each z-slice computes a K-chunk partial (f32, no bias) of Q or K.
// 6 z-slices x 256 tiles = 1536 blocks = exact 3 blocks/CU (48KB LDS).
struct QKJob { const short* A[3]; const short* B[3]; float* P; int kbeg; int kend; };
struct QKJobs { QKJob j[6]; };

__global__ __launch_bounds__(256, 3) void gemm_qk(QKJobs jobs, int K, int N)
{
  __shared__ short As[3][4096] __attribute__((aligned(16)));
  __shared__ short Bs[3][4096] __attribute__((aligned(16)));
  const int z = blockIdx.z;
  const int nwg  = gridDim.x * gridDim.y;
  const int flat = blockIdx.y * gridDim.x + blockIdx.x;
  const int swz  = (flat & 7) * (nwg >> 3) + (flat >> 3);
  const int bn = (swz % gridDim.x) * 128;
  const int bm = (swz / gridDim.x) * 128;

  const int t = threadIdx.x, lane = t & 63;
  const int wid = t >> 6, wr = wid >> 1, wc = wid & 1;
  const int l15 = lane & 15, kg = lane >> 4;
  const int srow = t >> 2;
  const int sc   = ((t & 3) ^ ((srow + (srow >> 2)) & 3)) * 8;

  int aoff[4], boff[4];
#pragma unroll
  for (int m = 0; m < 4; ++m) {
    const int ra = wr * 64 + m * 16 + l15;
    aoff[m] = ra * 32 + ((kg ^ ((ra + (ra >> 2)) & 3)) << 3);
    const int rb = wc * 64 + m * 16 + l15;
    boff[m] = rb * 32 + ((kg ^ ((rb + (rb >> 2)) & 3)) << 3);
  }

  f32x4 acc[4][4];
#pragma unroll
  for (int m = 0; m < 4; ++m)
#pragma unroll
    for (int n = 0; n < 4; ++n) acc[m][n] = (f32x4){0.f,0.f,0.f,0.f};

  const size_t aofs0 = (size_t)(bm + srow) * K + sc;
  const size_t bofs0 = (size_t)(bn + srow) * K + sc;
  const size_t half  = (size_t)64 * K;

  const int kbeg = jobs.j[z].kbeg, kend = jobs.j[z].kend;
  for (int kk = kbeg; kk < kend; kk += 32) {
    __syncthreads();
#pragma unroll
    for (int l = 0; l < 3; ++l) {
      gload16(jobs.j[z].A[l] + aofs0 + kk,        &As[l][t * 8]);
      gload16(jobs.j[z].A[l] + aofs0 + half + kk, &As[l][2048 + t * 8]);
      gload16(jobs.j[z].B[l] + bofs0 + kk,        &Bs[l][t * 8]);
      gload16(jobs.j[z].B[l] + bofs0 + half + kk, &Bs[l][2048 + t * 8]);
    }
    __syncthreads();
    bf16x8 a0[4], a1[4], a2[4], b[4];
#pragma unroll
    for (int m = 0; m < 4; ++m) {
      a0[m] = *(const bf16x8*)&As[0][aoff[m]];
      a1[m] = *(const bf16x8*)&As[1][aoff[m]];
      a2[m] = *(const bf16x8*)&As[2][aoff[m]];
    }
#pragma unroll
    for (int n = 0; n < 4; ++n) b[n] = *(const bf16x8*)&Bs[0][boff[n]];
#pragma unroll
    for (int m = 0; m < 4; ++m)
#pragma unroll
      for (int n = 0; n < 4; ++n) {
        acc[m][n] = __builtin_amdgcn_mfma_f32_16x16x32_bf16(a0[m], b[n], acc[m][n], 0, 0, 0);
        acc[m][n] = __builtin_amdgcn_mfma_f32_16x16x32_bf16(a1[m], b[n], acc[m][n], 0, 0, 0);
        acc[m][n] = __builtin_amdgcn_mfma_f32_16x16x32_bf16(a2[m], b[n], acc[m][n], 0, 0, 0);
      }
#pragma unroll
    for (int n = 0; n < 4; ++n) b[n] = *(const bf16x8*)&Bs[1][boff[n]];
#pragma unroll
    for (int m = 0; m < 4; ++m)
#pragma unroll
      for (int n = 0; n < 4; ++n) {
        acc[m][n] = __builtin_amdgcn_mfma_f32_16x16x32_bf16(a0[m], b[n], acc[m][n], 0, 0, 0);
        acc[m][n] = __builtin_amdgcn_mfma_f32_16x16x32_bf16(a1[m], b[n], acc[m][n], 0, 0, 0);
      }
#pragma unroll
    for (int n = 0; n < 4; ++n) b[n] = *(const bf16x8*)&Bs[2][boff[n]];
#pragma unroll
    for (int m = 0; m < 4; ++m)
#pragma unroll
      for (int n = 0; n < 4; ++n)
        acc[m][n] = __builtin_amdgcn_mfma_f32_16x16x32_bf16(a0[m], b[n], acc[m][n], 0, 0, 0);
  }

  float* P = jobs.j[z].P;
#pragma unroll
  for (int m = 0; m < 4; ++m) {
    const int row0 = bm + wr*64 + m*16 + kg*4;
#pragma unroll
    for (int n = 0; n < 4; ++n) {
      const int col = bn + wc*64 + n*16 + l15;
#pragma unroll
      for (int q = 0; q < 4; ++q)
        P[(size_t)(row0 + q) * N + col] = acc[m][n][q];
    }
  }
}

// combine: out = p0+p1+p2+bias (both Q and K in one launch, float4 x2/thread)
__global__ void qk_combine(const float* q0, const float* q1, const float* q2,
                           const float* bq, float* Qo,
                           const float* k0, const float* k1, const float* k2,
                           const float* bk, float* Ko)
{
  const size_t i = ((size_t)blockIdx.x * 256 + threadIdx.x) * 8;
  const int col = (int)(i & (DM_ - 1));
#define CMB8_(p0, p1, p2, bb, oo)                                            \
  {                                                                          \
    const float4 x0 = *(const float4*)((p0) + i);                            \
    const float4 x1 = *(const float4*)((p1) + i);                            \
    const float4 x2 = *(const float4*)((p2) + i);                            \
    const float4 y0 = *(const float4*)((p0) + i + 4);                        \
    const float4 y1 = *(const float4*)((p1) + i + 4);                        \
    const float4 y2 = *(const float4*)((p2) + i + 4);                        \
    const float4 b0 = *(const float4*)((bb) + col);                          \
    const float4 b1 = *(const float4*)((bb) + col + 4);                      \
    float4 r0, r1;                                                           \
    r0.x = x0.x + x1.x + x2.x + b0.x; r0.y = x0.y + x1.y + x2.y + b0.y;      \
    r0.z = x0.z + x1.z + x2.z + b0.z; r0.w = x0.w + x1.w + x2.w + b0.w;      \
    r1.x = y0.x + y1.x + y2.x + b1.x; r1.y = y0.y + y1.y + y2.y + b1.y;      \
    r1.z = y0.z + y1.z + y2.z + b1.z; r1.w = y0.w + y1.w + y2.w + b1.w;      \
    *(float4*)((oo) + i) = r0;                                               \
    *(float4*)((oo) + i + 4) = r1;                                           \
  }
  CMB8_(q0, q1, q2, bq, Qo)
  CMB8_(k0, k1, k2, bk, Ko)
#undef CMB8_
}

// ---------------- single-limb GEMM, double-buffered LDS (round-26) --------
struct FJob {
  const short* A[3];
  const short* B[3];
  const float* bias;
  float* C;       // nullable
  short* Ch;      // nullable: rne-bf16 of output
  int relu;
};

__global__ __launch_bounds__(256, 3) void gemm_one(FJob job, int K, int N)
{
  __shared__ short As[2][4096] __attribute__((aligned(16)));
  __shared__ short Bs[2][4096] __attribute__((aligned(16)));
  const int nwg  = gridDim.x * gridDim.y;
  const int flat = blockIdx.y * gridDim.x + blockIdx.x;
  const int swz  = (flat & 7) * (nwg >> 3) + (flat >> 3);
  const int bn = (swz % gridDim.x) * 128;
  const int bm = (swz / gridDim.x) * 128;

  const int t = threadIdx.x, lane = t & 63;
  const int wid = t >> 6, wr = wid >> 1, wc = wid & 1;
  const int l15 = lane & 15, kg = lane >> 4;
  const int srow = t >> 2;
  const int sc   = ((t & 3) ^ ((srow + (srow >> 2)) & 3)) * 8;

  int aoff[4], boff[4];
#pragma unroll
  for (int m = 0; m < 4; ++m) {
    const int ra = wr * 64 + m * 16 + l15;
    aoff[m] = ra * 32 + ((kg ^ ((ra + (ra >> 2)) & 3)) << 3);
    const int rb = wc * 64 + m * 16 + l15;
    boff[m] = rb * 32 + ((kg ^ ((rb + (rb >> 2)) & 3)) << 3);
  }

  f32x4 acc[4][4];
#pragma unroll
  for (int m = 0; m < 4; ++m)
#pragma unroll
    for (int n = 0; n < 4; ++n) acc[m][n] = (f32x4){0.f,0.f,0.f,0.f};

  const size_t aofs0 = (size_t)(bm + srow) * K + sc;
  const size_t bofs0 = (size_t)(bn + srow) * K + sc;
  const size_t half  = (size_t)64 * K;

  gload16(job.A[0] + aofs0,        &As[0][t * 8]);
  gload16(job.A[0] + aofs0 + half, &As[0][2048 + t * 8]);
  gload16(job.B[0] + bofs0,        &Bs[0][t * 8]);
  gload16(job.B[0] + bofs0 + half, &Bs[0][2048 + t * 8]);
  __syncthreads();

  int cur = 0;
  for (int kk = 0; kk < K; kk += 32) {
    const int nxt = kk + 32;
    if (nxt < K) {
      const int nb = cur ^ 1;
      gload16(job.A[0] + aofs0 + nxt,        &As[nb][t * 8]);
      gload16(job.A[0] + aofs0 + half + nxt, &As[nb][2048 + t * 8]);
      gload16(job.B[0] + bofs0 + nxt,        &Bs[nb][t * 8]);
      gload16(job.B[0] + bofs0 + half + nxt, &Bs[nb][2048 + t * 8]);
    }
    bf16x8 a[4], b[4];
#pragma unroll
    for (int m = 0; m < 4; ++m) a[m] = *(const bf16x8*)&As[cur][aoff[m]];
#pragma unroll
    for (int n = 0; n < 4; ++n) b[n] = *(const bf16x8*)&Bs[cur][boff[n]];
#pragma unroll
    for (int m = 0; m < 4; ++m)
#pragma unroll
      for (int n = 0; n < 4; ++n)
        acc[m][n] = __builtin_amdgcn_mfma_f32_16x16x32_bf16(a[m], b[n], acc[m][n], 0, 0, 0);
    __syncthreads();
    cur ^= 1;
  }

  const float* bias = job.bias;
  float* C  = job.C;
  short* Ch = job.Ch;
  const int relu = job.relu;
  float bv[4];
#pragma unroll
  for (int n = 0; n < 4; ++n) bv[n] = bias[bn + wc*64 + n*16 + l15];
#pragma unroll
  for (int m = 0; m < 4; ++m) {
    const int row0 = bm + wr*64 + m*16 + kg*4;
#pragma unroll
    for (int n = 0; n < 4; ++n) {
      const int col = bn + wc*64 + n*16 + l15;
#pragma unroll
      for (int q = 0; q < 4; ++q) {
        float o = acc[m][n][q] + bv[n];
        if (relu) o = fmaxf(o, 0.f);
        const size_t off = (size_t)(row0 + q) * N + col;
        if (C)  C[off]  = o;
        if (Ch) Ch[off] = (short)bf16rne(o);
      }
    }
  }
}

// ---------------- sampled QK^T -> M scores (round-20 verified) ------------
__global__ __launch_bounds__(256, 2) void qks_m_kernel(
    const float* __restrict__ Q, const float* __restrict__ K,
    const int* __restrict__ idx, float* __restrict__ Mout)
{
  __shared__ int sidx[64 * U_];
  const int p = blockIdx.x;
  const int g  = (p & 7) + (((p >> 3) & 7) << 3);
  const int q16 = p >> 6;
  const int l0 = q16 * 64;
  const int tid = threadIdx.x;
  for (int i = tid; i < 64 * U_; i += 256) sidx[i] = idx[l0 * U_ + i];
  __syncthreads();

  const int ll = tid >> 2, dq = tid & 3;
  const int l = l0 + ll;
  const int h = g & (H_ - 1), b = g >> 4;
  const size_t rowb = (size_t)(b * L_) * DM_ + h * DH_;
  const float* qrow = Q + rowb + (size_t)l * DM_ + dq * 4;
  float4 qv[4];
#pragma unroll
  for (int jj = 0; jj < 4; ++jj) qv[jj] = *(const float4*)(qrow + jj * 16);

  const int* ip = &sidx[ll * U_];
  float mx = -__builtin_inff();
  float sm = 0.f;
#pragma unroll 5
  for (int s = 0; s < U_; ++s) {
    const float* krow = K + rowb + (size_t)ip[s] * DM_ + dq * 4;
    const float4 k0 = *(const float4*)(krow);
    const float4 k1 = *(const float4*)(krow + 16);
    const float4 k2 = *(const float4*)(krow + 32);
    const float4 k3 = *(const float4*)(krow + 48);
    float a0 = 0.f, a1 = 0.f, a2 = 0.f, a3 = 0.f;
    a0 = fmaf(qv[0].x, k0.x, a0); a0 = fmaf(qv[0].y, k0.y, a0);
    a0 = fmaf(qv[0].z, k0.z, a0); a0 = fmaf(qv[0].w, k0.w, a0);
    a1 = fmaf(qv[1].x, k1.x, a1); a1 = fmaf(qv[1].y, k1.y, a1);
    a1 = fmaf(qv[1].z, k1.z, a1); a1 = fmaf(qv[1].w, k1.w, a1);
    a2 = fmaf(qv[2].x, k2.x, a2); a2 = fmaf(qv[2].y, k2.y, a2);
    a2 = fmaf(qv[2].z, k2.z, a2); a2 = fmaf(qv[2].w, k2.w, a2);
    a3 = fmaf(qv[3].x, k3.x, a3); a3 = fmaf(qv[3].y, k3.y, a3);
    a3 = fmaf(qv[3].z, k3.z, a3); a3 = fmaf(qv[3].w, k3.w, a3);
    float a = (a0 + a1) + (a2 + a3);
    a += __shfl_xor(a, 1, 64);
    a += __shfl_xor(a, 2, 64);
    mx = fmaxf(mx, a);
    sm += a;
  }
  if (dq == 0) Mout[g * L_ + l] = mx - sm * (1.0f / 1024.0f);
}

// ---------------- top-35 indices per (b,h) (round-27: wave-shuffle) -------
// Same comparator as before (max value, min index on ties) -> identical
// indices; replaces the 9-barrier LDS tree with a 64-lane shfl_xor reduce
// (1 barrier pair per iteration instead of 9).
__global__ __launch_bounds__(256) void topk_kernel(
    const float* __restrict__ M, int* __restrict__ Mtop)
{
  const int bh  = blockIdx.x;
  const int tid = threadIdx.x;
  const int lane = tid & 63, wv = tid >> 6;
  __shared__ float vals[L_];
  __shared__ float rv[4];
  __shared__ int   ri[4];
  for (int i = tid; i < L_; i += 256) vals[i] = M[(size_t)bh * L_ + i];
  __syncthreads();
  for (int t = 0; t < U_; ++t) {
    float best = -__builtin_inff();
    int   bi   = L_;
    for (int i = tid; i < L_; i += 256) {
      const float v = vals[i];
      if (v > best) { best = v; bi = i; }
    }
#pragma unroll
    for (int d = 1; d < 64; d <<= 1) {
      const float ov = __shfl_xor(best, d, 64);
      const int   oi = __shfl_xor(bi, d, 64);
      if (ov > best || (ov == best && oi < bi)) { best = ov; bi = oi; }
    }
    if (lane == 0) { rv[wv] = best; ri[wv] = bi; }
    __syncthreads();
    if (tid == 0) {
      float bb = rv[0]; int bj = ri[0];
#pragma unroll
      for (int w = 1; w < 4; ++w)
        if (rv[w] > bb || (rv[w] == bb && ri[w] < bj)) { bb = rv[w]; bj = ri[w]; }
      Mtop[bh * U_ + t] = bj;
      vals[bj] = -__builtin_inff();
    }
    __syncthreads();
  }
}

// ---------------- attention: 3-kernel k-split (round-22 verified) ---------
__global__ __launch_bounds__(256) void attn_score(
    const float* __restrict__ Q, const float* __restrict__ K,
    const int* __restrict__ Mtop, uint32_t* __restrict__ Pg, int masked)
{
  __shared__ float qs[U_ * DH_];
  __shared__ int   rowsL[U_ + 1];
  const int p = blockIdx.x;
  const int xcd = p & 7, idx2 = p >> 3;
  const int bh = xcd + ((idx2 & 7) << 3);
  const int ks = idx2 >> 3;
  const int h = bh & (H_ - 1), b = bh >> 4;
  const int tid = threadIdx.x;
  const size_t kvbase = (size_t)(b * L_) * DM_ + h * DH_;

  if (tid < U_) rowsL[tid] = Mtop[bh * U_ + tid];
  __syncthreads();
  for (int i = tid; i < U_ * DH_; i += 256)
    qs[i] = Q[kvbase + (size_t)rowsL[i >> 6] * DM_ + (i & 63)];
  __syncthreads();

  const int grp = tid >> 2, dq = tid & 3;
  const int k = ks * 64 + grp;
  const float* kp = K + kvbase + (size_t)k * DM_ + dq * 16;
  const float4 kv0 = *(const float4*)(kp);
  const float4 kv1 = *(const float4*)(kp + 4);
  const float4 kv2 = *(const float4*)(kp + 8);
  const float4 kv3 = *(const float4*)(kp + 12);

#define DOT_EXP_U(uu, out)                                                  \
  {                                                                         \
    const float4* qp = (const float4*)&qs[(uu) * 64 + dq * 16];             \
    const float4 q0 = qp[0], q1 = qp[1], q2 = qp[2], q3 = qp[3];            \
    float x0 = 0.f, x1 = 0.f;                                               \
    x0 = fmaf(q0.x, kv0.x, x0); x0 = fmaf(q0.y, kv0.y, x0);                 \
    x0 = fmaf(q0.z, kv0.z, x0); x0 = fmaf(q0.w, kv0.w, x0);                 \
    x1 = fmaf(q1.x, kv1.x, x1); x1 = fmaf(q1.y, kv1.y, x1);                 \
    x1 = fmaf(q1.z, kv1.z, x1); x1 = fmaf(q1.w, kv1.w, x1);                 \
    x0 = fmaf(q2.x, kv2.x, x0); x0 = fmaf(q2.y, kv2.y, x0);                 \
    x0 = fmaf(q2.z, kv2.z, x0); x0 = fmaf(q2.w, kv2.w, x0);                 \
    x1 = fmaf(q3.x, kv3.x, x1); x1 = fmaf(q3.y, kv3.y, x1);                 \
    x1 = fmaf(q3.z, kv3.z, x1); x1 = fmaf(q3.w, kv3.w, x1);                 \
    float a = x0 + x1;                                                      \
    a += __shfl_xor(a, 1, 64);                                              \
    a += __shfl_xor(a, 2, 64);                                              \
    float v = a * 0.125f;                                                   \
    if (masked && k > rowsL[(uu)]) v = -__builtin_inff();                   \
    out = expf(v);                                                          \
  }

  uint32_t pk[18];
#pragma unroll
  for (int j = 0; j < 17; ++j) {
    float e0, e1;
    DOT_EXP_U(2 * j, e0);
    DOT_EXP_U(2 * j + 1, e1);
    pk[j] = bf16rne(e0) | (bf16rne(e1) << 16);
  }
  {
    float e;
    DOT_EXP_U(34, e);
    pk[17] = bf16rne(e);
  }
#undef DOT_EXP_U

  if (dq == 0) {
    uint32_t* prow = Pg + (size_t)bh * (L_ * 18) + (size_t)k * 18;
#pragma unroll
    for (int j = 0; j < 18; ++j) prow[j] = pk[j];
  }
}

__global__ __launch_bounds__(256) void attn_pv(
    const float* __restrict__ V, const uint32_t* __restrict__ Pg,
    float* __restrict__ Opart, float* __restrict__ Dpart)
{
  __shared__ uint32_t Pl[64 * 18];
  const int p = blockIdx.x;
  const int xcd = p & 7, idx2 = p >> 3;
  const int bh = xcd + ((idx2 & 7) << 3);
  const int ks = idx2 >> 3;
  const int h = bh & (H_ - 1), b = bh >> 4;
  const int tid = threadIdx.x, lane = tid & 63, wid = tid >> 6;
  const size_t kvbase = (size_t)(b * L_) * DM_ + h * DH_;

  const uint32_t* ps = Pg + (size_t)bh * (L_ * 18) + (size_t)(ks * 64) * 18;
  for (int i = tid; i < 64 * 18; i += 256) Pl[i] = ps[i];
  __syncthreads();

  float acc[9], dd[9];
#pragma unroll
  for (int j = 0; j < 9; ++j) { acc[j] = 0.f; dd[j] = 0.f; }

  const float* vp = V + kvbase + (size_t)(ks * 64) * DM_ + lane;
  const int widh = wid >> 1;
  const int hi   = wid & 1;
#pragma unroll 8
  for (int kk = 0; kk < 64; ++kk) {
    const float v0 = vp[(size_t)kk * DM_];
    const uint32_t* pr = &Pl[kk * 18];
#pragma unroll
    for (int j = 0; j < 9; ++j) {
      if (wid + 4 * j < U_) {
        const uint32_t w = pr[widh + 2 * j];
        const float p2 = hi ? bitsf32(w & 0xFFFF0000u) : bitsf32(w << 16);
        acc[j] = fmaf(p2, v0, acc[j]);
        dd[j] += p2;
      }
    }
  }
  const int pb = (ks * 64 + bh) * U_;
#pragma unroll
  for (int j = 0; j < 9; ++j) {
    const int u = wid + 4 * j;
    if (u < U_) {
      Opart[(size_t)(pb + u) * 64 + lane] = acc[j];
      if (lane == 0) Dpart[pb + u] = dd[j];
    }
  }
}

__global__ void attn_reduce(const float* __restrict__ Opart,
                            const float* __restrict__ Dpart,
                            float* __restrict__ ctx_rows)
{
  const int bhu = blockIdx.x;
  const int bh = bhu / U_, u = bhu % U_;
  const int lane = threadIdx.x;
  float o = 0.f, dd = 0.f;
#pragma unroll
  for (int ks = 0; ks < KSP_; ++ks) {
    o  += Opart[(size_t)((ks * 64 + bh) * U_ + u) * 64 + lane];
    dd += Dpart[(ks * 64 + bh) * U_ + u];
  }
  ctx_rows[(size_t)bhu * 64 + lane] = o / dd;
}

// ---------------- cumsum / vmean / fill / scatter -------------------------
__global__ __launch_bounds__(256) void cumsum_kernel(
    const float* __restrict__ V, float* __restrict__ C)
{
  const int bh = blockIdx.x;
  const int h = bh & (H_ - 1), b = bh >> 4;
  const int d = threadIdx.x & 63, qq = threadIdx.x >> 6;
  __shared__ float chs[4][DH_];
  const size_t base = (size_t)b * L_ * DM_ + h * DH_ + d;
  float acc = 0.f;
  const int l0 = qq * 256;
  for (int l = l0; l < l0 + 256; ++l) acc += V[base + (size_t)l * DM_];
  chs[qq][d] = acc;
  __syncthreads();
  float off = 0.f;
  for (int j = 0; j < qq; ++j) off += chs[j][d];
  acc = off;
  for (int l = l0; l < l0 + 256; ++l) {
    acc += V[base + (size_t)l * DM_];
    C[base + (size_t)l * DM_] = acc;
  }
}

__global__ __launch_bounds__(256) void vmean_kernel(
    const float* __restrict__ V, float* __restrict__ vm)
{
  const int bh = blockIdx.x;
  const int h = bh & (H_ - 1), b = bh >> 4;
  const int d = threadIdx.x & 63, qq = threadIdx.x >> 6;
  __shared__ float chs[4][DH_];
  const size_t base = (size_t)b * L_ * DM_ + h * DH_ + d;
  float acc = 0.f;
  for (int l = qq * 256; l < qq * 256 + 256; ++l) acc += V[base + (size_t)l * DM_];
  chs[qq][d] = acc;
  __syncthreads();
  if (qq == 0)
    vm[bh * DH_ + d] = (chs[0][d] + chs[1][d] + chs[2][d] + chs[3][d]) * (1.0f / 1024.0f);
}

__global__ void fill_kernel(const float* __restrict__ vm, float* __restrict__ C)
{
  const size_t i = (size_t)blockIdx.x * 256 + threadIdx.x;
  const int d = (int)(i & 63);
  const int h = (int)((i >> 6) & (H_ - 1));
  const int b = (int)(i >> 20);
  C[i] = vm[(b * H_ + h) * DH_ + d];
}

__global__ void scatter_kernel(const float* __restrict__ ctx_rows,
                               const int* __restrict__ Mtop, float* __restrict__ C)
{
  const int bhu = blockIdx.x;
  const int u  = bhu % U_;
  const int bh = bhu / U_;
  const int h = bh & (H_ - 1), b = bh >> 4;
  const int row = Mtop[bh * U_ + u];
  C[(size_t)(b * L_ + row) * DM_ + h * DH_ + threadIdx.x] =
      ctx_rows[(size_t)bhu * DH_ + threadIdx.x];
}

// ---------------- LayerNorm(xa + xb), optional limb outputs ---------------
__global__ __launch_bounds__(256) void ln_kernel(
    const float* __restrict__ xa, const float* __restrict__ xb,
    const float* __restrict__ g, const float* __restrict__ bt,
    float* __restrict__ out, short* __restrict__ oh,
    short* __restrict__ om, short* __restrict__ ol)
{
  const int row = blockIdx.x;
  const int tid = threadIdx.x;
  __shared__ float v[DM_];
  __shared__ float red[256];
  float s = 0.f;
  for (int i = tid; i < DM_; i += 256) {
    const float t = xa[(size_t)row * DM_ + i] + xb[(size_t)row * DM_ + i];
    v[i] = t; s += t;
  }
  red[tid] = s; __syncthreads();
  for (int st = 128; st > 0; st >>= 1) { if (tid < st) red[tid] += red[tid+st]; __syncthreads(); }
  const float mean = red[0] * (1.0f / DM_);
  __syncthreads();
  float s2 = 0.f;
  for (int i = tid; i < DM_; i += 256) { const float dd = v[i] - mean; s2 += dd * dd; }
  red[tid] = s2; __syncthreads();
  for (int st = 128; st > 0; st >>= 1) { if (tid < st) red[tid] += red[tid+st]; __syncthreads(); }
  const float rstd = rsqrtf(red[0] * (1.0f / DM_) + 1e-5f);
  __syncthreads();
  for (int i = tid; i < DM_; i += 256) {
    const size_t idx = (size_t)row * DM_ + i;
    const float o = (v[i] - mean) * rstd * g[i] + bt[i];
    out[idx] = o;
    if (oh) {
      const uint32_t h = bf16rne(o);
      oh[idx] = (short)h;
      if (om) {
        const float r = o - bf16tof(h);
        const uint32_t m = bf16rne(r);
        om[idx] = (short)m;
        ol[idx] = (short)bf16rne(r - bf16tof(m));
      }
    }
  }
}

// ---------------- host orchestration --------------------------------------
extern "C" void kernel_launch(void* const* d_in, const int* in_sizes, int n_in,
                              void* d_out, int out_size, void* d_ws, size_t ws_size,
                              hipStream_t stream)
{
  (void)in_sizes; (void)n_in; (void)out_size; (void)ws_size;
  const float* x    = (const float*)d_in[0];
  const float* enc  = (const float*)d_in[1];
  const float* saWq = (const float*)d_in[2];  const float* sabq = (const float*)d_in[3];
  const float* saWk = (const float*)d_in[4];  const float* sabk = (const float*)d_in[5];
  const float* saWv = (const float*)d_in[6];  const float* sabv = (const float*)d_in[7];
  const float* saWo = (const float*)d_in[8];  const float* sabo = (const float*)d_in[9];
  const float* caWq = (const float*)d_in[10]; const float* cabq = (const float*)d_in[11];
  const float* caWk = (const float*)d_in[12]; const float* cabk = (const float*)d_in[13];
  const float* caWv = (const float*)d_in[14]; const float* cabv = (const float*)d_in[15];
  const float* caWo = (const float*)d_in[16]; const float* cabo = (const float*)d_in[17];
  const float* fW1  = (const float*)d_in[18]; const float* fb1  = (const float*)d_in[19];
  const float* fW2  = (const float*)d_in[20]; const float* fb2  = (const float*)d_in[21];
  const float* l1g  = (const float*)d_in[22]; const float* l1b  = (const float*)d_in[23];
  const float* l2g  = (const float*)d_in[24]; const float* l2b  = (const float*)d_in[25];
  const float* l3g  = (const float*)d_in[26]; const float* l3b  = (const float*)d_in[27];

  float* ws = (float*)d_ws;
  const size_t SL = (size_t)MROWS_ * DM_;
  float* bufQ = ws;
  float* bufK = ws + SL;
  float* bufV = ws + 2 * SL;
  float* bufC = ws + 3 * SL;
  float* xcur = ws + 4 * SL;
  float* tmp  = ws + 5 * SL;
  float* smallp = ws + 6 * SL;
  int*   idxb = (int*)smallp;
  float* Mbuf = smallp + 36864;
  int*   Mtop = (int*)(smallp + 36864 + 65536);
  float* ctxr = smallp + 36864 + 65536 + 2304;
  float* vm   = ctxr + 143360;

  uint32_t* Pg    = (uint32_t*)bufC;
  float*    Opart = bufC + 1179648;
  float*    Dpart = Opart + (size_t)KSP_ * 64 * U_ * 64;

  const size_t M1 = 1024u * 1024u;
  short* wreg = (short*)(ws + 6 * SL + 262144);
  short* areg = wreg + 8 * M1;
  short* Wqh = wreg;          short* Wqm = wreg + 1*M1; short* Wql = wreg + 2*M1;
  short* Wkh = wreg + 3*M1;   short* Wkm = wreg + 4*M1; short* Wkl = wreg + 5*M1;
  short* Wvh = wreg + 6*M1;   short* Woh = wreg + 7*M1;
  short* f1h = wreg;          short* f2h = wreg + 4*M1;
  short* xh = areg;           short* xm = areg + 4*M1;  short* xl = areg + 8*M1;
  short* eh = areg + 12*M1;   short* em = areg + 16*M1; short* el = areg + 20*M1;
  short* bCh = areg + 12*M1;
  short* hidh = (short*)bufQ;
  float* extra = (float*)(areg + 24 * M1);   // 16MB f32, round-27 (cross Qp2)

  uint32_t k1a, k1b, k2a, k2b;
  tf2x32(0u, 42u, 0u, 0u, k1a, k1b);
  tf2x32(0u, 42u, 0u, 1u, k2a, k2b);
  uint32_t kb1a, kb1b, kb2a, kb2b;
  tf2x32(k1a, k1b, 0u, 1u, kb1a, kb1b);
  tf2x32(k2a, k2b, 0u, 1u, kb2a, kb2b);

  const dim3 thr(256);
  const int gIdx = (IDXN_ + 255) / 256;
  const int n8 = (int)(SL / 8);

  const dim3 gP1(DM_ / 128, MROWS_ / 128, 1);   // (8,32)
  const dim3 gQK(DM_ / 128, MROWS_ / 128, 6);   // (8,32,6): Q x3 chunks, K x3
  const dim3 gF1(FF_ / 128, MROWS_ / 128, 1);   // (32,32)
  const int gCmb = (int)(SL / 8 / 256);         // 2048 blocks

  // ============ self attention (masked) ============
  {
    TSJobs T = {};
    T.j[0] = { saWq, Wqh, Wqm, Wql, DM_, DM_, 3, 256 };
    T.j[1] = { saWk, Wkh, Wkm, Wkl, DM_, DM_, 3, 256 };
    T.j[2] = { saWv, Wvh, nullptr, nullptr, DM_, DM_, 1, 256 };
    T.j[3] = { saWo, Woh, nullptr, nullptr, DM_, DM_, 1, 256 };
    T.cnt = 4;
    tsplit_batch<<<1024, thr, 0, stream>>>(T);
  }
  rsplit_kernel<3><<<n8 / 256, thr, 0, stream>>>(x, xh, xm, xl, n8);
  {
    // K-chunks: [0,352) [352,704) [704,1024). Partials -> dead buffers.
    QKJobs J = {};
    J.j[0] = { {xh, xm, xl}, {Wqh, Wqm, Wql}, bufQ, 0, 352 };
    J.j[1] = { {xh, xm, xl}, {Wqh, Wqm, Wql}, bufC, 352, 704 };
    J.j[2] = { {xh, xm, xl}, {Wqh, Wqm, Wql}, xcur, 704, 1024 };
    J.j[3] = { {xh, xm, xl}, {Wkh, Wkm, Wkl}, bufK, 0, 352 };
    J.j[4] = { {xh, xm, xl}, {Wkh, Wkm, Wkl}, bufV, 352, 704 };
    J.j[5] = { {xh, xm, xl}, {Wkh, Wkm, Wkl}, tmp, 704, 1024 };
    gemm_qk<<<gQK, thr, 0, stream>>>(J, DM_, DM_);
    qk_combine<<<gCmb, thr, 0, stream>>>(bufQ, bufC, xcur, sabq, bufQ,
                                         bufK, bufV, tmp, sabk, bufK);
  }
  {
    FJob J = { {xh, nullptr, nullptr}, {Wvh, nullptr, nullptr}, sabv, bufV, nullptr, 0 };
    gemm_one<<<gP1, thr, 0, stream>>>(J, DM_, DM_);
  }
  idx_kernel<<<gIdx, thr, 0, stream>>>(kb1a, kb1b, idxb);
  qks_m_kernel<<<1024, thr, 0, stream>>>(bufQ, bufK, idxb, Mbuf);
  topk_kernel<<<B_ * H_, thr, 0, stream>>>(Mbuf, Mtop);
  attn_score<<<B_ * H_ * KSC_, thr, 0, stream>>>(bufQ, bufK, Mtop, Pg, 1);
  attn_pv<<<B_ * H_ * KSP_, thr, 0, stream>>>(bufV, Pg, Opart, Dpart);
  attn_reduce<<<B_ * H_ * U_, dim3(64), 0, stream>>>(Opart, Dpart, ctxr);
  cumsum_kernel<<<B_ * H_, thr, 0, stream>>>(bufV, bufC);
  scatter_kernel<<<B_ * H_ * U_, dim3(64), 0, stream>>>(ctxr, Mtop, bufC);
  rsplit_kernel<1><<<n8 / 256, thr, 0, stream>>>(bufC, bCh, nullptr, nullptr, n8);
  {
    FJob J = { {bCh, nullptr, nullptr}, {Woh, nullptr, nullptr}, sabo, tmp, nullptr, 0 };
    gemm_one<<<gP1, thr, 0, stream>>>(J, DM_, DM_);
  }
  ln_kernel<<<MROWS_, thr, 0, stream>>>(x, tmp, l1g, l1b, xcur, xh, xm, xl);

  // ============ cross attention (unmasked) ============
  {
    TSJobs T = {};
    T.j[0] = { caWq, Wqh, Wqm, Wql, DM_, DM_, 3, 256 };
    T.j[1] = { caWk, Wkh, Wkm, Wkl, DM_, DM_, 3, 256 };
    T.j[2] = { caWv, Wvh, nullptr, nullptr, DM_, DM_, 1, 256 };
    T.j[3] = { caWo, Woh, nullptr, nullptr, DM_, DM_, 1, 256 };
    T.cnt = 4;
    tsplit_batch<<<1024, thr, 0, stream>>>(T);
  }
  rsplit_kernel<3><<<n8 / 256, thr, 0, stream>>>(enc, eh, em, el, n8);
  {
    // xcur is live here (ln1 out) -> use `extra` for Qp2 instead.
    QKJobs J = {};
    J.j[0] = { {xh, xm, xl}, {Wqh, Wqm, Wql}, bufQ, 0, 352 };
    J.j[1] = { {xh, xm, xl}, {Wqh, Wqm, Wql}, bufC, 352, 704 };
    J.j[2] = { {xh, xm, xl}, {Wqh, Wqm, Wql}, extra, 704, 1024 };
    J.j[3] = { {eh, em, el}, {Wkh, Wkm, Wkl}, bufK, 0, 352 };
    J.j[4] = { {eh, em, el}, {Wkh, Wkm, Wkl}, bufV, 352, 704 };
    J.j[5] = { {eh, em, el}, {Wkh, Wkm, Wkl}, tmp, 704, 1024 };
    gemm_qk<<<gQK, thr, 0, stream>>>(J, DM_, DM_);
    qk_combine<<<gCmb, thr, 0, stream>>>(bufQ, bufC, extra, cabq, bufQ,
                                         bufK, bufV, tmp, cabk, bufK);
  }
  {
    FJob J = { {eh, nullptr, nullptr}, {Wvh, nullptr, nullptr}, cabv, bufV, nullptr, 0 };
    gemm_one<<<gP1, thr, 0, stream>>>(J, DM_, DM_);
  }
  idx_kernel<<<gIdx, thr, 0, stream>>>(kb2a, kb2b, idxb);
  qks_m_kernel<<<1024, thr, 0, stream>>>(bufQ, bufK, idxb, Mbuf);
  topk_kernel<<<B_ * H_, thr, 0, stream>>>(Mbuf, Mtop);
  attn_score<<<B_ * H_ * KSC_, thr, 0, stream>>>(bufQ, bufK, Mtop, Pg, 0);
  attn_pv<<<B_ * H_ * KSP_, thr, 0, stream>>>(bufV, Pg, Opart, Dpart);
  attn_reduce<<<B_ * H_ * U_, dim3(64), 0, stream>>>(Opart, Dpart, ctxr);
  vmean_kernel<<<B_ * H_, thr, 0, stream>>>(bufV, vm);
  fill_kernel<<<(int)(SL / 256), thr, 0, stream>>>(vm, bufC);
  scatter_kernel<<<B_ * H_ * U_, dim3(64), 0, stream>>>(ctxr, Mtop, bufC);
  rsplit_kernel<1><<<n8 / 256, thr, 0, stream>>>(bufC, bCh, nullptr, nullptr, n8);
  {
    FJob J = { {bCh, nullptr, nullptr}, {Woh, nullptr, nullptr}, cabo, tmp, nullptr, 0 };
    gemm_one<<<gP1, thr, 0, stream>>>(J, DM_, DM_);
  }
  ln_kernel<<<MROWS_, thr, 0, stream>>>(xcur, tmp, l2g, l2b, xcur, xh, nullptr, nullptr);

  // ============ FFN ============
  {
    TSJobs T = {};
    T.j[0] = { fW1, f1h, nullptr, nullptr, DM_, FF_, 1, 1024 };
    T.j[1] = { fW2, f2h, nullptr, nullptr, FF_, DM_, 1, 1024 };
    T.cnt = 2;
    tsplit_batch<<<2048, thr, 0, stream>>>(T);
  }
  {
    FJob J = { {xh, nullptr, nullptr}, {f1h, nullptr, nullptr}, fb1, nullptr, hidh, 1 };
    gemm_one<<<gF1, thr, 0, stream>>>(J, DM_, FF_);
  }
  {
    FJob J = { {hidh, nullptr, nullptr}, {f2h, nullptr, nullptr}, fb2, tmp, nullptr, 0 };
    gemm_one<<<gP1, thr, 0, stream>>>(J, FF_, DM_);
  }
  ln_kernel<<<MROWS_, thr, 0, stream>>>(xcur, tmp, l3g, l3b, (float*)d_out,
                                        nullptr, nullptr, nullptr);
}

// Round 28
// 747.340 us; speedup vs baseline: 1.0601x; 1.0601x over previous
//
#include <hip/hip_runtime.h>
#include <cstdint>
#include <cstddef>

// Informer ProbSparse decoder layer.
// GEMMs: split-once bf16 limbs + FUSED multi-limb bf16 GEMM, 128x128 tile.
// Round-28: reverted round-27 K-split (structure-bound, not occupancy-bound:
// twice-measured ~50% MfmaUtil cap from the 2-barrier drain; partial traffic
// + combine ate the 3us gain). Launch-tail harvest: ONE merged weight-split
// launch (self+cross, 2048 blocks), ONE merged x/enc rsplit, ONE merged idx.
// bCh de-aliased from eh (now aliases dead bufQ). Wave-shuffle topk (r27).
// XOR chunk swizzle (src-side, rule #21) + XCD swizzle. Q/K: 6 pairings
// (~f32); V/O/FFN: 1 (gemm_one dbuf, r26-neutral). Attention: 3-kernel
// k-split; attn_score/attn_pv 4-lane-cooperative with XCD affinity.
#define B_     4
#define L_     1024
#define DM_    1024
#define H_     16
#define DH_    64
#define U_     35
#define FF_    4096
#define MROWS_ 4096
#define IDXN_  35840
#define KSC_   16
#define KSP_   16

typedef __attribute__((ext_vector_type(8))) short bf16x8;
typedef __attribute__((ext_vector_type(4))) float f32x4;

// ---------------- Threefry-2x32-20 (exact JAX semantics) ----------------
__host__ __device__ inline void tf2x32(uint32_t k0, uint32_t k1,
                                       uint32_t x0, uint32_t x1,
                                       uint32_t& y0, uint32_t& y1) {
  const uint32_t ks2 = k0 ^ k1 ^ 0x1BD11BDAu;
  uint32_t v0 = x0 + k0, v1 = x1 + k1;
#define ROTL_(x,d) (((x)<<(d))|((x)>>(32-(d))))
#define RND_(r) { v0 += v1; v1 = ROTL_(v1,(r)); v1 ^= v0; }
  RND_(13) RND_(15) RND_(26) RND_(6)   v0 += k1;  v1 += ks2 + 1u;
  RND_(17) RND_(29) RND_(16) RND_(24)  v0 += ks2; v1 += k0  + 2u;
  RND_(13) RND_(15) RND_(26) RND_(6)   v0 += k0;  v1 += k1  + 3u;
  RND_(17) RND_(29) RND_(16) RND_(24)  v0 += k1;  v1 += ks2 + 4u;
  RND_(13) RND_(15) RND_(26) RND_(6)   v0 += ks2; v1 += k0  + 5u;
#undef RND_
#undef ROTL_
  y0 = v0; y1 = v1;
}

// merged: both phases' sample indices in one launch (IDXN_ = 140*256 exact)
__global__ void idx2_kernel(uint32_t ka0, uint32_t ka1,
                            uint32_t kb0, uint32_t kb1,
                            int* __restrict__ ia, int* __restrict__ ib) {
  const int nb = IDXN_ / 256;
  int blk = blockIdx.x;
  uint32_t k0 = ka0, k1 = ka1; int* out = ia;
  if (blk >= nb) { blk -= nb; k0 = kb0; k1 = kb1; out = ib; }
  const int i = blk * 256 + threadIdx.x;
  uint32_t y0, y1;
  tf2x32(k0, k1, 0u, (uint32_t)i, y0, y1);
  out[i] = (int)((y0 ^ y1) & 1023u);
}

// ---------------- bf16 helpers --------------------------------------------
__device__ __forceinline__ uint32_t f32bits(float x) {
  union { float f; uint32_t u; } c; c.f = x; return c.u;
}
__device__ __forceinline__ float bitsf32(uint32_t u) {
  union { uint32_t u; float f; } c; c.u = u; return c.f;
}
__device__ __forceinline__ uint32_t bf16rne(float x) {
  const uint32_t u = f32bits(x);
  return (u + 0x7FFFu + ((u >> 16) & 1u)) >> 16;
}
__device__ __forceinline__ float bf16tof(uint32_t h) { return bitsf32(h << 16); }

__device__ __forceinline__ void split3(float x, uint32_t& h, uint32_t& m, uint32_t& l) {
  h = bf16rne(x); const float r  = x - bf16tof(h);
  m = bf16rne(r); const float r2 = r - bf16tof(m);
  l = bf16rne(r2);
}

// ---------------- async global -> LDS (16B per lane) ----------------------
__device__ __forceinline__ void gload16(const void* g, void* l) {
  __builtin_amdgcn_global_load_lds(
      (const __attribute__((address_space(1))) void*)g,
      (__attribute__((address_space(3))) void*)l, 16, 0, 0);
}

// ---------------- batched transpose-split (round-24/28: up to 8 jobs) -----
struct TSJob { const float* W; short* Th; short* Tm; short* Tl; int K; int N; int limbs; int nblk; };
struct TSJobs { TSJob j[8]; int cnt; };

__global__ __launch_bounds__(256) void tsplit_batch(TSJobs jobs)
{
  __shared__ float tile[64][65];
  int local = blockIdx.x;
  int ji = 0;
  while (ji < jobs.cnt - 1 && local >= jobs.j[ji].nblk) { local -= jobs.j[ji].nblk; ++ji; }
  const TSJob J = jobs.j[ji];
  const int ntiles = J.N >> 6;
  const int n0 = (local % ntiles) * 64;
  const int k0 = (local / ntiles) * 64;

  const int t = threadIdx.x;
  const int r = t >> 2, c0 = (t & 3) * 16;
  const float* src = J.W + (size_t)(k0 + r) * J.N + n0 + c0;
  const float4 v0 = *(const float4*)src;
  const float4 v1 = *(const float4*)(src + 4);
  const float4 v2 = *(const float4*)(src + 8);
  const float4 v3 = *(const float4*)(src + 12);
  float* tr = &tile[r][c0];
  tr[0]=v0.x; tr[1]=v0.y; tr[2]=v0.z; tr[3]=v0.w;
  tr[4]=v1.x; tr[5]=v1.y; tr[6]=v1.z; tr[7]=v1.w;
  tr[8]=v2.x; tr[9]=v2.y; tr[10]=v2.z; tr[11]=v2.w;
  tr[12]=v3.x; tr[13]=v3.y; tr[14]=v3.z; tr[15]=v3.w;
  __syncthreads();
  uint32_t ph[8], pm[8], pl[8];
#pragma unroll
  for (int j = 0; j < 16; j += 2) {
    uint32_t h0,m0,l0,h1,m1,l1;
    split3(tile[c0 + j][r], h0, m0, l0);
    split3(tile[c0 + j + 1][r], h1, m1, l1);
    ph[j>>1] = h0 | (h1 << 16);
    pm[j>>1] = m0 | (m1 << 16);
    pl[j>>1] = l0 | (l1 << 16);
  }
  const size_t ob = (size_t)(n0 + r) * J.K + k0 + c0;
  *(uint4*)(J.Th + ob)     = make_uint4(ph[0], ph[1], ph[2], ph[3]);
  *(uint4*)(J.Th + ob + 8) = make_uint4(ph[4], ph[5], ph[6], ph[7]);
  if (J.limbs == 3) {
    *(uint4*)(J.Tm + ob)     = make_uint4(pm[0], pm[1], pm[2], pm[3]);
    *(uint4*)(J.Tm + ob + 8) = make_uint4(pm[4], pm[5], pm[6], pm[7]);
    *(uint4*)(J.Tl + ob)     = make_uint4(pl[0], pl[1], pl[2], pl[3]);
    *(uint4*)(J.Tl + ob + 8) = make_uint4(pl[4], pl[5], pl[6], pl[7]);
  }
}

// ---------------- row split: X (f32) -> limbs (bf16), elementwise ---------
template<int LIMBS>
__global__ void rsplit_kernel(const float* __restrict__ X, short* __restrict__ Th,
                              short* __restrict__ Tm, short* __restrict__ Tl, int n8)
{
  const int i = blockIdx.x * 256 + threadIdx.x;
  if (i >= n8) return;
  const float4 a = ((const float4*)X)[2*i], b = ((const float4*)X)[2*i+1];
  const float v[8] = {a.x,a.y,a.z,a.w,b.x,b.y,b.z,b.w};
  uint32_t ph[4], pm[4], pl[4];
#pragma unroll
  for (int j = 0; j < 4; ++j) {
    uint32_t h0,m0,l0,h1,m1,l1;
    split3(v[2*j], h0, m0, l0);
    split3(v[2*j+1], h1, m1, l1);
    ph[j] = h0 | (h1 << 16); pm[j] = m0 | (m1 << 16); pl[j] = l0 | (l1 << 16);
  }
  ((uint4*)Th)[i] = make_uint4(ph[0], ph[1], ph[2], ph[3]);
  if (LIMBS == 3) {
    ((uint4*)Tm)[i] = make_uint4(pm[0], pm[1], pm[2], pm[3]);
    ((uint4*)Tl)[i] = make_uint4(pl[0], pl[1], pl[2], pl[3]);
  }
}

// merged 3-limb row split for x and enc in one launch (round-28)
__global__ void rsplit2_kernel(const float* __restrict__ Xa, short* ah, short* am, short* al,
                               const float* __restrict__ Xb, short* bh, short* bm, short* bl,
                               int n8)
{
  int i = blockIdx.x * 256 + threadIdx.x;
  const float* X = Xa; short* Th = ah; short* Tm = am; short* Tl = al;
  if (i >= n8) { i -= n8; X = Xb; Th = bh; Tm = bm; Tl = bl; }
  const float4 a = ((const float4*)X)[2*i], b = ((const float4*)X)[2*i+1];
  const float v[8] = {a.x,a.y,a.z,a.w,b.x,b.y,b.z,b.w};
  uint32_t ph[4], pm[4], pl[4];
#pragma unroll
  for (int j = 0; j < 4; ++j) {
    uint32_t h0,m0,l0,h1,m1,l1;
    split3(v[2*j], h0, m0, l0);
    split3(v[2*j+1], h1, m1, l1);
    ph[j] = h0 | (h1 << 16); pm[j] = m0 | (m1 << 16); pl[j] = l0 | (l1 << 16);
  }
  ((uint4*)Th)[i] = make_uint4(ph[0], ph[1], ph[2], ph[3]);
  ((uint4*)Tm)[i] = make_uint4(pm[0], pm[1], pm[2], pm[3]);
  ((uint4*)Tl)[i] = make_uint4(pl[0], pl[1], pl[2], pl[3]);
}

// ---------------- fused multi-limb bf16 GEMM (128x128, round-22 verified) -
struct FJob {
  const short* A[3];
  const short* B[3];
  const float* bias;
  float* C;       // nullable
  short* Ch;      // nullable: rne-bf16 of output
  int relu;
};
struct FJobs { FJob j[3]; };

template<int NL>
__global__ __launch_bounds__(256, 3) void gemm_fused(FJobs jobs, int K, int N)
{
  __shared__ short As[NL][4096] __attribute__((aligned(16)));
  __shared__ short Bs[NL][4096] __attribute__((aligned(16)));
  const int z = blockIdx.z;
  const int nwg  = gridDim.x * gridDim.y;
  const int flat = blockIdx.y * gridDim.x + blockIdx.x;
  const int swz  = (flat & 7) * (nwg >> 3) + (flat >> 3);
  const int bn = (swz % gridDim.x) * 128;
  const int bm = (swz / gridDim.x) * 128;

  const int t = threadIdx.x, lane = t & 63;
  const int wid = t >> 6, wr = wid >> 1, wc = wid & 1;
  const int l15 = lane & 15, kg = lane >> 4;
  const int srow = t >> 2;
  const int sc   = ((t & 3) ^ ((srow + (srow >> 2)) & 3)) * 8;

  int aoff[4], boff[4];
#pragma unroll
  for (int m = 0; m < 4; ++m) {
    const int ra = wr * 64 + m * 16 + l15;
    aoff[m] = ra * 32 + ((kg ^ ((ra + (ra >> 2)) & 3)) << 3);
    const int rb = wc * 64 + m * 16 + l15;
    boff[m] = rb * 32 + ((kg ^ ((rb + (rb >> 2)) & 3)) << 3);
  }

  f32x4 acc[4][4];
#pragma unroll
  for (int m = 0; m < 4; ++m)
#pragma unroll
    for (int n = 0; n < 4; ++n) acc[m][n] = (f32x4){0.f,0.f,0.f,0.f};

  const size_t aofs0 = (size_t)(bm + srow) * K + sc;
  const size_t bofs0 = (size_t)(bn + srow) * K + sc;
  const size_t half  = (size_t)64 * K;

  for (int kk = 0; kk < K; kk += 32) {
    __syncthreads();
#pragma unroll
    for (int l = 0; l < NL; ++l) {
      gload16(jobs.j[z].A[l] + aofs0 + kk,        &As[l][t * 8]);
      gload16(jobs.j[z].A[l] + aofs0 + half + kk, &As[l][2048 + t * 8]);
      gload16(jobs.j[z].B[l] + bofs0 + kk,        &Bs[l][t * 8]);
      gload16(jobs.j[z].B[l] + bofs0 + half + kk, &Bs[l][2048 + t * 8]);
    }
    __syncthreads();
    if (NL == 1) {
      bf16x8 a[4], b[4];
#pragma unroll
      for (int m = 0; m < 4; ++m) a[m] = *(const bf16x8*)&As[0][aoff[m]];
#pragma unroll
      for (int n = 0; n < 4; ++n) b[n] = *(const bf16x8*)&Bs[0][boff[n]];
#pragma unroll
      for (int m = 0; m < 4; ++m)
#pragma unroll
        for (int n = 0; n < 4; ++n)
          acc[m][n] = __builtin_amdgcn_mfma_f32_16x16x32_bf16(a[m], b[n], acc[m][n], 0, 0, 0);
    } else {
      bf16x8 a0[4], a1[4], a2[4], b[4];
#pragma unroll
      for (int m = 0; m < 4; ++m) {
        a0[m] = *(const bf16x8*)&As[0][aoff[m]];
        a1[m] = *(const bf16x8*)&As[1][aoff[m]];
        a2[m] = *(const bf16x8*)&As[2][aoff[m]];
      }
#pragma unroll
      for (int n = 0; n < 4; ++n) b[n] = *(const bf16x8*)&Bs[0][boff[n]];
#pragma unroll
      for (int m = 0; m < 4; ++m)
#pragma unroll
        for (int n = 0; n < 4; ++n) {
          acc[m][n] = __builtin_amdgcn_mfma_f32_16x16x32_bf16(a0[m], b[n], acc[m][n], 0, 0, 0);
          acc[m][n] = __builtin_amdgcn_mfma_f32_16x16x32_bf16(a1[m], b[n], acc[m][n], 0, 0, 0);
          acc[m][n] = __builtin_amdgcn_mfma_f32_16x16x32_bf16(a2[m], b[n], acc[m][n], 0, 0, 0);
        }
#pragma unroll
      for (int n = 0; n < 4; ++n) b[n] = *(const bf16x8*)&Bs[1][boff[n]];
#pragma unroll
      for (int m = 0; m < 4; ++m)
#pragma unroll
        for (int n = 0; n < 4; ++n) {
          acc[m][n] = __builtin_amdgcn_mfma_f32_16x16x32_bf16(a0[m], b[n], acc[m][n], 0, 0, 0);
          acc[m][n] = __builtin_amdgcn_mfma_f32_16x16x32_bf16(a1[m], b[n], acc[m][n], 0, 0, 0);
        }
#pragma unroll
      for (int n = 0; n < 4; ++n) b[n] = *(const bf16x8*)&Bs[2][boff[n]];
#pragma unroll
      for (int m = 0; m < 4; ++m)
#pragma unroll
        for (int n = 0; n < 4; ++n)
          acc[m][n] = __builtin_amdgcn_mfma_f32_16x16x32_bf16(a0[m], b[n], acc[m][n], 0, 0, 0);
    }
  }

  const float* bias = jobs.j[z].bias;
  float* C  = jobs.j[z].C;
  short* Ch = jobs.j[z].Ch;
  const int relu = jobs.j[z].relu;
  float bv[4];
#pragma unroll
  for (int n = 0; n < 4; ++n) bv[n] = bias[bn + wc*64 + n*16 + l15];
#pragma unroll
  for (int m = 0; m < 4; ++m) {
    const int row0 = bm + wr*64 + m*16 + kg*4;
#pragma unroll
    for (int n = 0; n < 4; ++n) {
      const int col = bn + wc*64 + n*16 + l15;
#pragma unroll
      for (int q = 0; q < 4; ++q) {
        float o = acc[m][n][q] + bv[n];
        if (relu) o = fmaxf(o, 0.f);
        const size_t off = (size_t)(row0 + q) * N + col;
        if (C)  C[off]  = o;
        if (Ch) Ch[off] = (short)bf16rne(o);
      }
    }
  }
}

// ---------------- single-limb GEMM, double-buffered LDS (round-26) --------
__global__ __launch_bounds__(256, 3) void gemm_one(FJob job, int K, int N)
{
  __shared__ short As[2][4096] __attribute__((aligned(16)));
  __shared__ short Bs[2][4096] __attribute__((aligned(16)));
  const int nwg  = gridDim.x * gridDim.y;
  const int flat = blockIdx.y * gridDim.x + blockIdx.x;
  const int swz  = (flat & 7) * (nwg >> 3) + (flat >> 3);
  const int bn = (swz % gridDim.x) * 128;
  const int bm = (swz / gridDim.x) * 128;

  const int t = threadIdx.x, lane = t & 63;
  const int wid = t >> 6, wr = wid >> 1, wc = wid & 1;
  const int l15 = lane & 15, kg = lane >> 4;
  const int srow = t >> 2;
  const int sc   = ((t & 3) ^ ((srow + (srow >> 2)) & 3)) * 8;

  int aoff[4], boff[4];
#pragma unroll
  for (int m = 0; m < 4; ++m) {
    const int ra = wr * 64 + m * 16 + l15;
    aoff[m] = ra * 32 + ((kg ^ ((ra + (ra >> 2)) & 3)) << 3);
    const int rb = wc * 64 + m * 16 + l15;
    boff[m] = rb * 32 + ((kg ^ ((rb + (rb >> 2)) & 3)) << 3);
  }

  f32x4 acc[4][4];
#pragma unroll
  for (int m = 0; m < 4; ++m)
#pragma unroll
    for (int n = 0; n < 4; ++n) acc[m][n] = (f32x4){0.f,0.f,0.f,0.f};

  const size_t aofs0 = (size_t)(bm + srow) * K + sc;
  const size_t bofs0 = (size_t)(bn + srow) * K + sc;
  const size_t half  = (size_t)64 * K;

  gload16(job.A[0] + aofs0,        &As[0][t * 8]);
  gload16(job.A[0] + aofs0 + half, &As[0][2048 + t * 8]);
  gload16(job.B[0] + bofs0,        &Bs[0][t * 8]);
  gload16(job.B[0] + bofs0 + half, &Bs[0][2048 + t * 8]);
  __syncthreads();

  int cur = 0;
  for (int kk = 0; kk < K; kk += 32) {
    const int nxt = kk + 32;
    if (nxt < K) {
      const int nb = cur ^ 1;
      gload16(job.A[0] + aofs0 + nxt,        &As[nb][t * 8]);
      gload16(job.A[0] + aofs0 + half + nxt, &As[nb][2048 + t * 8]);
      gload16(job.B[0] + bofs0 + nxt,        &Bs[nb][t * 8]);
      gload16(job.B[0] + bofs0 + half + nxt, &Bs[nb][2048 + t * 8]);
    }
    bf16x8 a[4], b[4];
#pragma unroll
    for (int m = 0; m < 4; ++m) a[m] = *(const bf16x8*)&As[cur][aoff[m]];
#pragma unroll
    for (int n = 0; n < 4; ++n) b[n] = *(const bf16x8*)&Bs[cur][boff[n]];
#pragma unroll
    for (int m = 0; m < 4; ++m)
#pragma unroll
      for (int n = 0; n < 4; ++n)
        acc[m][n] = __builtin_amdgcn_mfma_f32_16x16x32_bf16(a[m], b[n], acc[m][n], 0, 0, 0);
    __syncthreads();
    cur ^= 1;
  }

  const float* bias = job.bias;
  float* C  = job.C;
  short* Ch = job.Ch;
  const int relu = job.relu;
  float bv[4];
#pragma unroll
  for (int n = 0; n < 4; ++n) bv[n] = bias[bn + wc*64 + n*16 + l15];
#pragma unroll
  for (int m = 0; m < 4; ++m) {
    const int row0 = bm + wr*64 + m*16 + kg*4;
#pragma unroll
    for (int n = 0; n < 4; ++n) {
      const int col = bn + wc*64 + n*16 + l15;
#pragma unroll
      for (int q = 0; q < 4; ++q) {
        float o = acc[m][n][q] + bv[n];
        if (relu) o = fmaxf(o, 0.f);
        const size_t off = (size_t)(row0 + q) * N + col;
        if (C)  C[off]  = o;
        if (Ch) Ch[off] = (short)bf16rne(o);
      }
    }
  }
}

// ---------------- sampled QK^T -> M scores (round-20 verified) ------------
__global__ __launch_bounds__(256, 2) void qks_m_kernel(
    const float* __restrict__ Q, const float* __restrict__ K,
    const int* __restrict__ idx, float* __restrict__ Mout)
{
  __shared__ int sidx[64 * U_];
  const int p = blockIdx.x;
  const int g  = (p & 7) + (((p >> 3) & 7) << 3);
  const int q16 = p >> 6;
  const int l0 = q16 * 64;
  const int tid = threadIdx.x;
  for (int i = tid; i < 64 * U_; i += 256) sidx[i] = idx[l0 * U_ + i];
  __syncthreads();

  const int ll = tid >> 2, dq = tid & 3;
  const int l = l0 + ll;
  const int h = g & (H_ - 1), b = g >> 4;
  const size_t rowb = (size_t)(b * L_) * DM_ + h * DH_;
  const float* qrow = Q + rowb + (size_t)l * DM_ + dq * 4;
  float4 qv[4];
#pragma unroll
  for (int jj = 0; jj < 4; ++jj) qv[jj] = *(const float4*)(qrow + jj * 16);

  const int* ip = &sidx[ll * U_];
  float mx = -__builtin_inff();
  float sm = 0.f;
#pragma unroll 5
  for (int s = 0; s < U_; ++s) {
    const float* krow = K + rowb + (size_t)ip[s] * DM_ + dq * 4;
    const float4 k0 = *(const float4*)(krow);
    const float4 k1 = *(const float4*)(krow + 16);
    const float4 k2 = *(const float4*)(krow + 32);
    const float4 k3 = *(const float4*)(krow + 48);
    float a0 = 0.f, a1 = 0.f, a2 = 0.f, a3 = 0.f;
    a0 = fmaf(qv[0].x, k0.x, a0); a0 = fmaf(qv[0].y, k0.y, a0);
    a0 = fmaf(qv[0].z, k0.z, a0); a0 = fmaf(qv[0].w, k0.w, a0);
    a1 = fmaf(qv[1].x, k1.x, a1); a1 = fmaf(qv[1].y, k1.y, a1);
    a1 = fmaf(qv[1].z, k1.z, a1); a1 = fmaf(qv[1].w, k1.w, a1);
    a2 = fmaf(qv[2].x, k2.x, a2); a2 = fmaf(qv[2].y, k2.y, a2);
    a2 = fmaf(qv[2].z, k2.z, a2); a2 = fmaf(qv[2].w, k2.w, a2);
    a3 = fmaf(qv[3].x, k3.x, a3); a3 = fmaf(qv[3].y, k3.y, a3);
    a3 = fmaf(qv[3].z, k3.z, a3); a3 = fmaf(qv[3].w, k3.w, a3);
    float a = (a0 + a1) + (a2 + a3);
    a += __shfl_xor(a, 1, 64);
    a += __shfl_xor(a, 2, 64);
    mx = fmaxf(mx, a);
    sm += a;
  }
  if (dq == 0) Mout[g * L_ + l] = mx - sm * (1.0f / 1024.0f);
}

// ---------------- top-35 indices per (b,h) (round-27: wave-shuffle) -------
__global__ __launch_bounds__(256) void topk_kernel(
    const float* __restrict__ M, int* __restrict__ Mtop)
{
  const int bh  = blockIdx.x;
  const int tid = threadIdx.x;
  const int lane = tid & 63, wv = tid >> 6;
  __shared__ float vals[L_];
  __shared__ float rv[4];
  __shared__ int   ri[4];
  for (int i = tid; i < L_; i += 256) vals[i] = M[(size_t)bh * L_ + i];
  __syncthreads();
  for (int t = 0; t < U_; ++t) {
    float best = -__builtin_inff();
    int   bi   = L_;
    for (int i = tid; i < L_; i += 256) {
      const float v = vals[i];
      if (v > best) { best = v; bi = i; }
    }
#pragma unroll
    for (int d = 1; d < 64; d <<= 1) {
      const float ov = __shfl_xor(best, d, 64);
      const int   oi = __shfl_xor(bi, d, 64);
      if (ov > best || (ov == best && oi < bi)) { best = ov; bi = oi; }
    }
    if (lane == 0) { rv[wv] = best; ri[wv] = bi; }
    __syncthreads();
    if (tid == 0) {
      float bb = rv[0]; int bj = ri[0];
#pragma unroll
      for (int w = 1; w < 4; ++w)
        if (rv[w] > bb || (rv[w] == bb && ri[w] < bj)) { bb = rv[w]; bj = ri[w]; }
      Mtop[bh * U_ + t] = bj;
      vals[bj] = -__builtin_inff();
    }
    __syncthreads();
  }
}

// ---------------- attention: 3-kernel k-split (round-22 verified) ---------
__global__ __launch_bounds__(256) void attn_score(
    const float* __restrict__ Q, const float* __restrict__ K,
    const int* __restrict__ Mtop, uint32_t* __restrict__ Pg, int masked)
{
  __shared__ float qs[U_ * DH_];
  __shared__ int   rowsL[U_ + 1];
  const int p = blockIdx.x;
  const int xcd = p & 7, idx2 = p >> 3;
  const int bh = xcd + ((idx2 & 7) << 3);
  const int ks = idx2 >> 3;
  const int h = bh & (H_ - 1), b = bh >> 4;
  const int tid = threadIdx.x;
  const size_t kvbase = (size_t)(b * L_) * DM_ + h * DH_;

  if (tid < U_) rowsL[tid] = Mtop[bh * U_ + tid];
  __syncthreads();
  for (int i = tid; i < U_ * DH_; i += 256)
    qs[i] = Q[kvbase + (size_t)rowsL[i >> 6] * DM_ + (i & 63)];
  __syncthreads();

  const int grp = tid >> 2, dq = tid & 3;
  const int k = ks * 64 + grp;
  const float* kp = K + kvbase + (size_t)k * DM_ + dq * 16;
  const float4 kv0 = *(const float4*)(kp);
  const float4 kv1 = *(const float4*)(kp + 4);
  const float4 kv2 = *(const float4*)(kp + 8);
  const float4 kv3 = *(const float4*)(kp + 12);

#define DOT_EXP_U(uu, out)                                                  \
  {                                                                         \
    const float4* qp = (const float4*)&qs[(uu) * 64 + dq * 16];             \
    const float4 q0 = qp[0], q1 = qp[1], q2 = qp[2], q3 = qp[3];            \
    float x0 = 0.f, x1 = 0.f;                                               \
    x0 = fmaf(q0.x, kv0.x, x0); x0 = fmaf(q0.y, kv0.y, x0);                 \
    x0 = fmaf(q0.z, kv0.z, x0); x0 = fmaf(q0.w, kv0.w, x0);                 \
    x1 = fmaf(q1.x, kv1.x, x1); x1 = fmaf(q1.y, kv1.y, x1);                 \
    x1 = fmaf(q1.z, kv1.z, x1); x1 = fmaf(q1.w, kv1.w, x1);                 \
    x0 = fmaf(q2.x, kv2.x, x0); x0 = fmaf(q2.y, kv2.y, x0);                 \
    x0 = fmaf(q2.z, kv2.z, x0); x0 = fmaf(q2.w, kv2.w, x0);                 \
    x1 = fmaf(q3.x, kv3.x, x1); x1 = fmaf(q3.y, kv3.y, x1);                 \
    x1 = fmaf(q3.z, kv3.z, x1); x1 = fmaf(q3.w, kv3.w, x1);                 \
    float a = x0 + x1;                                                      \
    a += __shfl_xor(a, 1, 64);                                              \
    a += __shfl_xor(a, 2, 64);                                              \
    float v = a * 0.125f;                                                   \
    if (masked && k > rowsL[(uu)]) v = -__builtin_inff();                   \
    out = expf(v);                                                          \
  }

  uint32_t pk[18];
#pragma unroll
  for (int j = 0; j < 17; ++j) {
    float e0, e1;
    DOT_EXP_U(2 * j, e0);
    DOT_EXP_U(2 * j + 1, e1);
    pk[j] = bf16rne(e0) | (bf16rne(e1) << 16);
  }
  {
    float e;
    DOT_EXP_U(34, e);
    pk[17] = bf16rne(e);
  }
#undef DOT_EXP_U

  if (dq == 0) {
    uint32_t* prow = Pg + (size_t)bh * (L_ * 18) + (size_t)k * 18;
#pragma unroll
    for (int j = 0; j < 18; ++j) prow[j] = pk[j];
  }
}

__global__ __launch_bounds__(256) void attn_pv(
    const float* __restrict__ V, const uint32_t* __restrict__ Pg,
    float* __restrict__ Opart, float* __restrict__ Dpart)
{
  __shared__ uint32_t Pl[64 * 18];
  const int p = blockIdx.x;
  const int xcd = p & 7, idx2 = p >> 3;
  const int bh = xcd + ((idx2 & 7) << 3);
  const int ks = idx2 >> 3;
  const int h = bh & (H_ - 1), b = bh >> 4;
  const int tid = threadIdx.x, lane = tid & 63, wid = tid >> 6;
  const size_t kvbase = (size_t)(b * L_) * DM_ + h * DH_;

  const uint32_t* ps = Pg + (size_t)bh * (L_ * 18) + (size_t)(ks * 64) * 18;
  for (int i = tid; i < 64 * 18; i += 256) Pl[i] = ps[i];
  __syncthreads();

  float acc[9], dd[9];
#pragma unroll
  for (int j = 0; j < 9; ++j) { acc[j] = 0.f; dd[j] = 0.f; }

  const float* vp = V + kvbase + (size_t)(ks * 64) * DM_ + lane;
  const int widh = wid >> 1;
  const int hi   = wid & 1;
#pragma unroll 8
  for (int kk = 0; kk < 64; ++kk) {
    const float v0 = vp[(size_t)kk * DM_];
    const uint32_t* pr = &Pl[kk * 18];
#pragma unroll
    for (int j = 0; j < 9; ++j) {
      if (wid + 4 * j < U_) {
        const uint32_t w = pr[widh + 2 * j];
        const float p2 = hi ? bitsf32(w & 0xFFFF0000u) : bitsf32(w << 16);
        acc[j] = fmaf(p2, v0, acc[j]);
        dd[j] += p2;
      }
    }
  }
  const int pb = (ks * 64 + bh) * U_;
#pragma unroll
  for (int j = 0; j < 9; ++j) {
    const int u = wid + 4 * j;
    if (u < U_) {
      Opart[(size_t)(pb + u) * 64 + lane] = acc[j];
      if (lane == 0) Dpart[pb + u] = dd[j];
    }
  }
}

__global__ void attn_reduce(const float* __restrict__ Opart,
                            const float* __restrict__ Dpart,
                            float* __restrict__ ctx_rows)
{
  const int bhu = blockIdx.x;
  const int bh = bhu / U_, u = bhu % U_;
  const int lane = threadIdx.x;
  float o = 0.f, dd = 0.f;
#pragma unroll
  for (int ks = 0; ks < KSP_; ++ks) {
    o  += Opart[(size_t)((ks * 64 + bh) * U_ + u) * 64 + lane];
    dd += Dpart[(ks * 64 + bh) * U_ + u];
  }
  ctx_rows[(size_t)bhu * 64 + lane] = o / dd;
}

// ---------------- cumsum / vmean / fill / scatter -------------------------
__global__ __launch_bounds__(256) void cumsum_kernel(
    const float* __restrict__ V, float* __restrict__ C)
{
  const int bh = blockIdx.x;
  const int h = bh & (H_ - 1), b = bh >> 4;
  const int d = threadIdx.x & 63, qq = threadIdx.x >> 6;
  __shared__ float chs[4][DH_];
  const size_t base = (size_t)b * L_ * DM_ + h * DH_ + d;
  float acc = 0.f;
  const int l0 = qq * 256;
  for (int l = l0; l < l0 + 256; ++l) acc += V[base + (size_t)l * DM_];
  chs[qq][d] = acc;
  __syncthreads();
  float off = 0.f;
  for (int j = 0; j < qq; ++j) off += chs[j][d];
  acc = off;
  for (int l = l0; l < l0 + 256; ++l) {
    acc += V[base + (size_t)l * DM_];
    C[base + (size_t)l * DM_] = acc;
  }
}

__global__ __launch_bounds__(256) void vmean_kernel(
    const float* __restrict__ V, float* __restrict__ vm)
{
  const int bh = blockIdx.x;
  const int h = bh & (H_ - 1), b = bh >> 4;
  const int d = threadIdx.x & 63, qq = threadIdx.x >> 6;
  __shared__ float chs[4][DH_];
  const size_t base = (size_t)b * L_ * DM_ + h * DH_ + d;
  float acc = 0.f;
  for (int l = qq * 256; l < qq * 256 + 256; ++l) acc += V[base + (size_t)l * DM_];
  chs[qq][d] = acc;
  __syncthreads();
  if (qq == 0)
    vm[bh * DH_ + d] = (chs[0][d] + chs[1][d] + chs[2][d] + chs[3][d]) * (1.0f / 1024.0f);
}

__global__ void fill_kernel(const float* __restrict__ vm, float* __restrict__ C)
{
  const size_t i = (size_t)blockIdx.x * 256 + threadIdx.x;
  const int d = (int)(i & 63);
  const int h = (int)((i >> 6) & (H_ - 1));
  const int b = (int)(i >> 20);
  C[i] = vm[(b * H_ + h) * DH_ + d];
}

__global__ void scatter_kernel(const float* __restrict__ ctx_rows,
                               const int* __restrict__ Mtop, float* __restrict__ C)
{
  const int bhu = blockIdx.x;
  const int u  = bhu % U_;
  const int bh = bhu / U_;
  const int h = bh & (H_ - 1), b = bh >> 4;
  const int row = Mtop[bh * U_ + u];
  C[(size_t)(b * L_ + row) * DM_ + h * DH_ + threadIdx.x] =
      ctx_rows[(size_t)bhu * DH_ + threadIdx.x];
}

// ---------------- LayerNorm(xa + xb), optional limb outputs ---------------
__global__ __launch_bounds__(256) void ln_kernel(
    const float* __restrict__ xa, const float* __restrict__ xb,
    const float* __restrict__ g, const float* __restrict__ bt,
    float* __restrict__ out, short* __restrict__ oh,
    short* __restrict__ om, short* __restrict__ ol)
{
  const int row = blockIdx.x;
  const int tid = threadIdx.x;
  __shared__ float v[DM_];
  __shared__ float red[256];
  float s = 0.f;
  for (int i = tid; i < DM_; i += 256) {
    const float t = xa[(size_t)row * DM_ + i] + xb[(size_t)row * DM_ + i];
    v[i] = t; s += t;
  }
  red[tid] = s; __syncthreads();
  for (int st = 128; st > 0; st >>= 1) { if (tid < st) red[tid] += red[tid+st]; __syncthreads(); }
  const float mean = red[0] * (1.0f / DM_);
  __syncthreads();
  float s2 = 0.f;
  for (int i = tid; i < DM_; i += 256) { const float dd = v[i] - mean; s2 += dd * dd; }
  red[tid] = s2; __syncthreads();
  for (int st = 128; st > 0; st >>= 1) { if (tid < st) red[tid] += red[tid+st]; __syncthreads(); }
  const float rstd = rsqrtf(red[0] * (1.0f / DM_) + 1e-5f);
  __syncthreads();
  for (int i = tid; i < DM_; i += 256) {
    const size_t idx = (size_t)row * DM_ + i;
    const float o = (v[i] - mean) * rstd * g[i] + bt[i];
    out[idx] = o;
    if (oh) {
      const uint32_t h = bf16rne(o);
      oh[idx] = (short)h;
      if (om) {
        const float r = o - bf16tof(h);
        const uint32_t m = bf16rne(r);
        om[idx] = (short)m;
        ol[idx] = (short)bf16rne(r - bf16tof(m));
      }
    }
  }
}

// ---------------- host orchestration --------------------------------------
extern "C" void kernel_launch(void* const* d_in, const int* in_sizes, int n_in,
                              void* d_out, int out_size, void* d_ws, size_t ws_size,
                              hipStream_t stream)
{
  (void)in_sizes; (void)n_in; (void)out_size; (void)ws_size;
  const float* x    = (const float*)d_in[0];
  const float* enc  = (const float*)d_in[1];
  const float* saWq = (const float*)d_in[2];  const float* sabq = (const float*)d_in[3];
  const float* saWk = (const float*)d_in[4];  const float* sabk = (const float*)d_in[5];
  const float* saWv = (const float*)d_in[6];  const float* sabv = (const float*)d_in[7];
  const float* saWo = (const float*)d_in[8];  const float* sabo = (const float*)d_in[9];
  const float* caWq = (const float*)d_in[10]; const float* cabq = (const float*)d_in[11];
  const float* caWk = (const float*)d_in[12]; const float* cabk = (const float*)d_in[13];
  const float* caWv = (const float*)d_in[14]; const float* cabv = (const float*)d_in[15];
  const float* caWo = (const float*)d_in[16]; const float* cabo = (const float*)d_in[17];
  const float* fW1  = (const float*)d_in[18]; const float* fb1  = (const float*)d_in[19];
  const float* fW2  = (const float*)d_in[20]; const float* fb2  = (const float*)d_in[21];
  const float* l1g  = (const float*)d_in[22]; const float* l1b  = (const float*)d_in[23];
  const float* l2g  = (const float*)d_in[24]; const float* l2b  = (const float*)d_in[25];
  const float* l3g  = (const float*)d_in[26]; const float* l3b  = (const float*)d_in[27];

  float* ws = (float*)d_ws;
  const size_t SL = (size_t)MROWS_ * DM_;
  float* bufQ = ws;
  float* bufK = ws + SL;
  float* bufV = ws + 2 * SL;
  float* bufC = ws + 3 * SL;
  float* xcur = ws + 4 * SL;
  float* tmp  = ws + 5 * SL;
  float* smallp = ws + 6 * SL;
  int*   idxb = (int*)smallp;
  float* Mbuf = smallp + 36864;
  int*   Mtop = (int*)(smallp + 36864 + 65536);
  float* ctxr = smallp + 36864 + 65536 + 2304;
  float* vm   = ctxr + 143360;

  uint32_t* Pg    = (uint32_t*)bufC;
  float*    Opart = bufC + 1179648;
  float*    Dpart = Opart + (size_t)KSP_ * 64 * U_ * 64;

  const size_t M1 = 1024u * 1024u;
  short* wreg = (short*)(ws + 6 * SL + 262144);
  // self weights: wreg[0..8M1)
  short* Wqh = wreg;          short* Wqm = wreg + 1*M1; short* Wql = wreg + 2*M1;
  short* Wkh = wreg + 3*M1;   short* Wkm = wreg + 4*M1; short* Wkl = wreg + 5*M1;
  short* Wvh = wreg + 6*M1;   short* Woh = wreg + 7*M1;
  // cross weights: wreg[8M1..16M1)  (round-28: split up-front in one launch)
  short* cWqh = wreg + 8*M1;  short* cWqm = wreg + 9*M1;  short* cWql = wreg + 10*M1;
  short* cWkh = wreg + 11*M1; short* cWkm = wreg + 12*M1; short* cWkl = wreg + 13*M1;
  short* cWvh = wreg + 14*M1; short* cWoh = wreg + 15*M1;
  // FFN weights alias the (dead-by-then) self Q/K limbs
  short* f1h = wreg;          short* f2h = wreg + 4*M1;
  short* areg = wreg + 16*M1;
  short* xh = areg;           short* xm = areg + 4*M1;  short* xl = areg + 8*M1;
  short* eh = areg + 12*M1;   short* em = areg + 16*M1; short* el = areg + 20*M1;
  short* bCh = (short*)bufQ;          // round-28: de-aliased from eh (bufQ dead then)
  int*   idxb2 = (int*)(areg + 24*M1);
  short* hidh = (short*)bufQ;

  uint32_t k1a, k1b, k2a, k2b;
  tf2x32(0u, 42u, 0u, 0u, k1a, k1b);
  tf2x32(0u, 42u, 0u, 1u, k2a, k2b);
  uint32_t kb1a, kb1b, kb2a, kb2b;
  tf2x32(k1a, k1b, 0u, 1u, kb1a, kb1b);
  tf2x32(k2a, k2b, 0u, 1u, kb2a, kb2b);

  const dim3 thr(256);
  const int n8 = (int)(SL / 8);

  const dim3 gP1(DM_ / 128, MROWS_ / 128, 1);   // (8,32)
  const dim3 gP2(DM_ / 128, MROWS_ / 128, 2);   // (8,32,2)
  const dim3 gF1(FF_ / 128, MROWS_ / 128, 1);   // (32,32)

  // ============ up-front independent work (round-28 merged launches) ======
  {
    TSJobs T = {};
    T.j[0] = { saWq, Wqh, Wqm, Wql, DM_, DM_, 3, 256 };
    T.j[1] = { saWk, Wkh, Wkm, Wkl, DM_, DM_, 3, 256 };
    T.j[2] = { saWv, Wvh, nullptr, nullptr, DM_, DM_, 1, 256 };
    T.j[3] = { saWo, Woh, nullptr, nullptr, DM_, DM_, 1, 256 };
    T.j[4] = { caWq, cWqh, cWqm, cWql, DM_, DM_, 3, 256 };
    T.j[5] = { caWk, cWkh, cWkm, cWkl, DM_, DM_, 3, 256 };
    T.j[6] = { caWv, cWvh, nullptr, nullptr, DM_, DM_, 1, 256 };
    T.j[7] = { caWo, cWoh, nullptr, nullptr, DM_, DM_, 1, 256 };
    T.cnt = 8;
    tsplit_batch<<<2048, thr, 0, stream>>>(T);
  }
  rsplit2_kernel<<<2 * (n8 / 256), thr, 0, stream>>>(x, xh, xm, xl,
                                                     enc, eh, em, el, n8);
  idx2_kernel<<<2 * (IDXN_ / 256), thr, 0, stream>>>(kb1a, kb1b, kb2a, kb2b,
                                                     idxb, idxb2);

  // ============ self attention (masked) ============
  {
    FJobs J = {};
    J.j[0] = { {xh, xm, xl}, {Wqh, Wqm, Wql}, sabq, bufQ, nullptr, 0 };
    J.j[1] = { {xh, xm, xl}, {Wkh, Wkm, Wkl}, sabk, bufK, nullptr, 0 };
    gemm_fused<3><<<gP2, thr, 0, stream>>>(J, DM_, DM_);
  }
  {
    FJob J = { {xh, nullptr, nullptr}, {Wvh, nullptr, nullptr}, sabv, bufV, nullptr, 0 };
    gemm_one<<<gP1, thr, 0, stream>>>(J, DM_, DM_);
  }
  qks_m_kernel<<<1024, thr, 0, stream>>>(bufQ, bufK, idxb, Mbuf);
  topk_kernel<<<B_ * H_, thr, 0, stream>>>(Mbuf, Mtop);
  attn_score<<<B_ * H_ * KSC_, thr, 0, stream>>>(bufQ, bufK, Mtop, Pg, 1);
  attn_pv<<<B_ * H_ * KSP_, thr, 0, stream>>>(bufV, Pg, Opart, Dpart);
  attn_reduce<<<B_ * H_ * U_, dim3(64), 0, stream>>>(Opart, Dpart, ctxr);
  cumsum_kernel<<<B_ * H_, thr, 0, stream>>>(bufV, bufC);
  scatter_kernel<<<B_ * H_ * U_, dim3(64), 0, stream>>>(ctxr, Mtop, bufC);
  rsplit_kernel<1><<<n8 / 256, thr, 0, stream>>>(bufC, bCh, nullptr, nullptr, n8);
  {
    FJob J = { {bCh, nullptr, nullptr}, {Woh, nullptr, nullptr}, sabo, tmp, nullptr, 0 };
    gemm_one<<<gP1, thr, 0, stream>>>(J, DM_, DM_);
  }
  ln_kernel<<<MROWS_, thr, 0, stream>>>(x, tmp, l1g, l1b, xcur, xh, xm, xl);

  // ============ cross attention (unmasked) ============
  {
    FJobs J = {};
    J.j[0] = { {xh, xm, xl}, {cWqh, cWqm, cWql}, cabq, bufQ, nullptr, 0 };
    J.j[1] = { {eh, em, el}, {cWkh, cWkm, cWkl}, cabk, bufK, nullptr, 0 };
    gemm_fused<3><<<gP2, thr, 0, stream>>>(J, DM_, DM_);
  }
  {
    FJob J = { {eh, nullptr, nullptr}, {cWvh, nullptr, nullptr}, cabv, bufV, nullptr, 0 };
    gemm_one<<<gP1, thr, 0, stream>>>(J, DM_, DM_);
  }
  qks_m_kernel<<<1024, thr, 0, stream>>>(bufQ, bufK, idxb2, Mbuf);
  topk_kernel<<<B_ * H_, thr, 0, stream>>>(Mbuf, Mtop);
  attn_score<<<B_ * H_ * KSC_, thr, 0, stream>>>(bufQ, bufK, Mtop, Pg, 0);
  attn_pv<<<B_ * H_ * KSP_, thr, 0, stream>>>(bufV, Pg, Opart, Dpart);
  attn_reduce<<<B_ * H_ * U_, dim3(64), 0, stream>>>(Opart, Dpart, ctxr);
  vmean_kernel<<<B_ * H_, thr, 0, stream>>>(bufV, vm);
  fill_kernel<<<(int)(SL / 256), thr, 0, stream>>>(vm, bufC);
  scatter_kernel<<<B_ * H_ * U_, dim3(64), 0, stream>>>(ctxr, Mtop, bufC);
  rsplit_kernel<1><<<n8 / 256, thr, 0, stream>>>(bufC, bCh, nullptr, nullptr, n8);
  {
    FJob J = { {bCh, nullptr, nullptr}, {cWoh, nullptr, nullptr}, cabo, tmp, nullptr, 0 };
    gemm_one<<<gP1, thr, 0, stream>>>(J, DM_, DM_);
  }
  ln_kernel<<<MROWS_, thr, 0, stream>>>(xcur, tmp, l2g, l2b, xcur, xh, nullptr, nullptr);

  // ============ FFN ============
  {
    TSJobs T = {};
    T.j[0] = { fW1, f1h, nullptr, nullptr, DM_, FF_, 1, 1024 };
    T.j[1] = { fW2, f2h, nullptr, nullptr, FF_, DM_, 1, 1024 };
    T.cnt = 2;
    tsplit_batch<<<2048, thr, 0, stream>>>(T);
  }
  {
    FJob J = { {xh, nullptr, nullptr}, {f1h, nullptr, nullptr}, fb1, nullptr, hidh, 1 };
    gemm_one<<<gF1, thr, 0, stream>>>(J, DM_, FF_);
  }
  {
    FJob J = { {hidh, nullptr, nullptr}, {f2h, nullptr, nullptr}, fb2, tmp, nullptr, 0 };
    gemm_one<<<gP1, thr, 0, stream>>>(J, FF_, DM_);
  }
  ln_kernel<<<MROWS_, thr, 0, stream>>>(xcur, tmp, l3g, l3b, (float*)d_out,
                                        nullptr, nullptr, nullptr);
}